// Round 11
// baseline (72.681 us; speedup 1.0000x reference)
//
#include <hip/hip_runtime.h>
#include <hip/hip_bf16.h>

// Problem constants
#define BATCH 2
#define CH 256
#define NH 8
#define HD 32
#define NPOS 2304            // 48*48
#define SCALE 0.17677669529663687f          // 32^-0.5
#define QSCALE 0.25503482f                  // SCALE * log2(e)
#define NSPLIT 3
#define KSPAN (NPOS / NSPLIT)               // 768 = 6 tiles of 128
#define NT (KSPAN / 128)                    // 6
#define QT (NPOS / 16)                      // 144 q-tiles

typedef __attribute__((ext_vector_type(8))) short short8;   // 8 x bf16 (4 VGPRs)
typedef __attribute__((ext_vector_type(4))) short short4e;  // 4 x bf16 (8B)
typedef __attribute__((ext_vector_type(4))) float f32x4;
typedef __attribute__((ext_vector_type(4))) unsigned int u32x4;
typedef __attribute__((ext_vector_type(2))) unsigned int u32x2;

__device__ __forceinline__ unsigned short f2bf(float f) {
    unsigned int u = __builtin_bit_cast(unsigned int, f);
    u += 0x7FFFu + ((u >> 16) & 1u);     // round-to-nearest-even
    return (unsigned short)(u >> 16);
}

// packed 2xbf16 <- 2xf32 (D.lo = cvt(a), D.hi = cvt(b)), RNE
__device__ __forceinline__ unsigned int cvt_pk_bf16(float a, float b) {
    unsigned int r;
    asm("v_cvt_pk_bf16_f32 %0, %1, %2" : "=v"(r) : "v"(a), "v"(b));
    return r;
}

// single-instruction 2^x
__device__ __forceinline__ float fast_exp2(float x) {
    float r;
    asm("v_exp_f32 %0, %1" : "=v"(r) : "v"(x));
    return r;
}

// async global->LDS, 16B per lane; LDS dest = uniform base + lane*16
#define GLOAD_LDS16(gsrc, ldst) \
    __builtin_amdgcn_global_load_lds( \
        (const __attribute__((address_space(1))) void*)(gsrc), \
        (__attribute__((address_space(3))) void*)(ldst), 16, 0, 0)

// ---------------------------------------------------------------------------
// Prep: fused weight-convert (blocks 0..255) + x transpose (blocks 256..1407).
// ---------------------------------------------------------------------------
__global__ __launch_bounds__(256) void prep(
    const float* __restrict__ Wq, const float* __restrict__ Wk,
    const float* __restrict__ Wv, const float* __restrict__ Wo,
    const float* __restrict__ x,
    unsigned short* __restrict__ wbf, unsigned short* __restrict__ xT)
{
    __shared__ float Ts[32][33];
    int id = blockIdx.x;
    int t = threadIdx.x;
    if (id < 256) {
        int which = id >> 6;
        const float* src = (which == 0) ? Wq : (which == 1) ? Wk : (which == 2) ? Wv : Wo;
        unsigned short* d = wbf + (size_t)which * CH * CH;
        int i = ((id & 63) * 256 + t) * 4;
        f32x4 v = *(const f32x4*)&src[i];
        short4e o;
        #pragma unroll
        for (int j = 0; j < 4; ++j) o[j] = (short)f2bf(v[j]);
        *(short4e*)&d[i] = o;
    } else {
        int tid = id - 256;
        int b = tid / 576;
        int rem = tid % 576;
        int c0 = (rem / 72) * 32;
        int n0 = (rem % 72) * 32;
        int col = t & 31, row = t >> 5;      // row 0..7
        #pragma unroll
        for (int i = 0; i < 4; ++i)
            Ts[row + i * 8][col] = x[((size_t)b * CH + c0 + row + i * 8) * NPOS + n0 + col];
        __syncthreads();
        #pragma unroll
        for (int i = 0; i < 4; ++i)
            xT[((size_t)b * NPOS + n0 + row + i * 8) * CH + c0 + col] = f2bf(Ts[col][row + i * 8]);
    }
}

// ---------------------------------------------------------------------------
// Fused QKV GEMM via bf16 MFMA. xT: [B][N][C] bf16. Wb: q|k|v bf16 [o][c].
// q,k bf16 [(b*NH+h)*N + n]*32 + d   (q pre-scaled by QSCALE = SCALE*log2e)
// v  bf16 [(b*NH+h)*32 + d]*N + pi(n)   (transposed, key-permuted per 128-blk)
// Block = 4 waves, tile 32o x 64n; wave owns 16o x 32n. Grid 576 blocks.
// V store: in-quad 4x4 shfl transpose -> one 8B store/lane/g.
// ---------------------------------------------------------------------------
__global__ __launch_bounds__(256) void qkv_gemm(
    const unsigned short* __restrict__ xT,
    const unsigned short* __restrict__ Wb,
    const float* __restrict__ bq, const float* __restrict__ bk,
    const float* __restrict__ bv,
    unsigned short* __restrict__ qout, unsigned short* __restrict__ kout,
    unsigned short* __restrict__ vout)
{
    int b = blockIdx.z;
    int n0 = blockIdx.x * 64;            // 36
    int o0 = blockIdx.y * 32;            // 8
    int t = threadIdx.x, w = t >> 6, lane = t & 63;
    int lo = lane & 15, hi = lane >> 4;
    int ob = o0 + (w & 1) * 16;
    int nb = n0 + (w >> 1) * 32;

    const unsigned short* Wq = Wb;
    const unsigned short* Wk = Wb + (size_t)CH * CH;
    const unsigned short* Wv = Wb + (size_t)2 * CH * CH;
    const unsigned short* xb = xT + ((size_t)b * NPOS + nb) * CH;

    f32x4 aq[2] = {}, ak[2] = {}, av[2] = {};

    for (int k0 = 0; k0 < CH; k0 += 32) {
        short8 wqf = *(const short8*)&Wq[(size_t)(ob + lo) * CH + k0 + hi * 8];
        short8 wkf = *(const short8*)&Wk[(size_t)(ob + lo) * CH + k0 + hi * 8];
        short8 wvf = *(const short8*)&Wv[(size_t)(ob + lo) * CH + k0 + hi * 8];
        #pragma unroll
        for (int g = 0; g < 2; ++g) {
            short8 xf = *(const short8*)&xb[(size_t)(g * 16 + lo) * CH + k0 + hi * 8];
            aq[g] = __builtin_amdgcn_mfma_f32_16x16x32_bf16(wqf, xf, aq[g], 0, 0, 0);
            ak[g] = __builtin_amdgcn_mfma_f32_16x16x32_bf16(wkf, xf, ak[g], 0, 0, 0);
            av[g] = __builtin_amdgcn_mfma_f32_16x16x32_bf16(wvf, xf, av[g], 0, 0, 0);
        }
    }

    int h = ob >> 5;
    int olow = (ob & 31) + hi * 4;
    int rr = lo & 3, qd = lo >> 2;
    #pragma unroll
    for (int g = 0; g < 2; ++g) {
        int n = nb + g * 16 + lo;
        size_t qkbase = ((size_t)(b * NH + h) * NPOS + n) * HD + olow;
        short4e pq, pk;
        #pragma unroll
        for (int r = 0; r < 4; ++r) {
            int o = ob + hi * 4 + r;
            pq[r] = (short)f2bf((aq[g][r] + bq[o]) * QSCALE);
            pk[r] = (short)f2bf(ak[g][r] + bk[o]);
        }
        *(short4e*)&qout[qkbase] = pq;
        *(short4e*)&kout[qkbase] = pk;

        // ---- V store: bias-add, 4x4 transpose across quad lanes, 8B store
        float v0 = av[g][0] + bv[ob + hi * 4 + 0];
        float v1 = av[g][1] + bv[ob + hi * 4 + 1];
        float v2 = av[g][2] + bv[ob + hi * 4 + 2];
        float v3 = av[g][3] + bv[ob + hi * 4 + 3];
        float p, r_;
        p = (rr & 1) ? v0 : v1; r_ = __shfl_xor(p, 1); if (rr & 1) v0 = r_; else v1 = r_;
        p = (rr & 1) ? v2 : v3; r_ = __shfl_xor(p, 1); if (rr & 1) v2 = r_; else v3 = r_;
        p = (rr & 2) ? v0 : v2; r_ = __shfl_xor(p, 2); if (rr & 2) v0 = r_; else v2 = r_;
        p = (rr & 2) ? v1 : v3; r_ = __shfl_xor(p, 2); if (rr & 2) v1 = r_; else v3 = r_;
        u32x2 pr;
        pr[0] = cvt_pk_bf16(v0, v1);
        pr[1] = cvt_pk_bf16(v2, v3);
        int nbase = nb + g * 16;             // 16-aligned
        int G = (nbase & 127) >> 4;          // key-group of this 16-run
        int pbase;
        if (G < 4) {
            pbase = G * 32 + qd * 8;
        } else {
            int gam = G & 3;
            pbase = (qd >= 2) ? (gam * 32 + (qd - 2) * 8 + 4)
                              : ((gam ^ 1) * 32 + (qd + 2) * 8 + 4);
        }
        int d = (ob & 31) + hi * 4 + rr;
        size_t vaddr = ((size_t)(b * NH + h) * HD + d) * NPOS + (nbase & ~127) + pbase;
        *(u32x2*)&vout[vaddr] = pr;
    }
}

// ---------------------------------------------------------------------------
// Flash attention partial, bf16 MFMA, 128-key tiles, split-K x3.
// 4 waves/block; EACH WAVE OWNS TWO q-tiles (qtA, qtB): K-fragments read
// from LDS once feed both QK^T MFMAs; V-fragments feed both PV chains ->
// per-qt staging, barrier, and LDS-read cost halve; 2x MFMA per staged tile.
// K/V staged via global_load_lds (16B), double-buffered, one barrier/tile.
// LDS source-pre-swizzled (K: blk^=row&3, V: blk^=row&15); swapped QK^T ->
// P lane-local; cvt_pk + one shfl_xor(32)/word with pi baked into V storage.
// grid (48, 18): id = x + 48y, 48%8==0 -> same (bh,split) -> same XCD.
// ---------------------------------------------------------------------------
__global__ __launch_bounds__(256) void attn_split(
    const unsigned short* __restrict__ Q,
    const unsigned short* __restrict__ K,
    const unsigned short* __restrict__ V,
    float* __restrict__ Opart,
    float* __restrict__ Lpart)
{
    const int N = NPOS;
    int xb_ = blockIdx.x;           // 0..47: (split, bh)
    int bh = xb_ & 15;
    int split = xb_ >> 4;           // 0..2
    int w = threadIdx.x >> 6;
    int qtA = blockIdx.y * 8 + w * 2;   // 0..143 (wave owns qtA, qtA+1)
    int qtB = qtA + 1;
    int lane = threadIdx.x & 63;
    int lo = lane & 15, hi = lane >> 4;
    bool upperhalf = lane >= 32;

    // double-buffered K/V tiles: 8KB each per buffer (32KB total)
    __shared__ unsigned short Ks[2][128 * HD];
    __shared__ unsigned short Vs[2][HD * 128];

    short8 qaA = *(const short8*)(Q + ((size_t)bh * N + qtA * 16 + lo) * HD + hi * 8);
    short8 qaB = *(const short8*)(Q + ((size_t)bh * N + qtB * 16 + lo) * HD + hi * 8);

    const unsigned short* Kb = K + (size_t)bh * N * HD;
    const unsigned short* Vb = V + (size_t)bh * HD * N;

    short8 ones;
    #pragma unroll
    for (int j = 0; j < 8; ++j) ones[j] = (short)0x3F80;   // bf16 1.0

    f32x4 oaccA[2] = {{0.f,0.f,0.f,0.f},{0.f,0.f,0.f,0.f}};
    f32x4 oaccB[2] = {{0.f,0.f,0.f,0.f},{0.f,0.f,0.f,0.f}};
    f32x4 laccA = {0.f,0.f,0.f,0.f};
    f32x4 laccB = {0.f,0.f,0.f,0.f};

    const int kbeg = split * KSPAN;

    // ---- staging: wave w covers chunks [w*128, w*128+128) of each 512-chunk tile
    auto stage = [&](int bidx, int k0) {
        #pragma unroll
        for (int j = 0; j < 2; ++j) {
            int L = w * 128 + j * 64 + lane;           // K chunk: row=L>>2, blk=L&3
            int row = L >> 2, blk = L & 3;
            const unsigned short* src = Kb + (size_t)(k0 + row) * HD + (blk ^ (row & 3)) * 8;
            GLOAD_LDS16(src, &Ks[bidx][(size_t)(w * 128 + j * 64) * 8]);
        }
        #pragma unroll
        for (int j = 0; j < 2; ++j) {
            int L = w * 128 + j * 64 + lane;           // V chunk: row=L>>4, blk=L&15
            int row = L >> 4, blk = L & 15;
            const unsigned short* src = Vb + (size_t)row * N + k0 + (blk ^ (row & 15)) * 8;
            GLOAD_LDS16(src, &Vs[bidx][(size_t)(w * 128 + j * 64) * 8]);
        }
    };

    // prologue: stage tile 0
    stage(0, kbeg);
    __syncthreads();                 // drains vmcnt + barrier

    int buf = 0;
    #pragma unroll
    for (int kt = 0; kt < NT; ++kt) {
        int k0 = kbeg + kt * 128;
        if (kt + 1 < NT) stage(buf ^ 1, k0 + 128);

        // ---- S^T = K Q^T, both q-tiles per kf read (kf reused)
        f32x4 sA[8], sB[8];
        __builtin_amdgcn_s_setprio(1);
        #pragma unroll
        for (int g = 0; g < 8; ++g) {
            short8 kf = *(const short8*)&Ks[buf][(g * 16 + lo) * HD + (hi ^ (lo & 3)) * 8];
            sA[g] = __builtin_amdgcn_mfma_f32_16x16x32_bf16(kf, qaA, (f32x4){0.f,0.f,0.f,0.f}, 0, 0, 0);
            sB[g] = __builtin_amdgcn_mfma_f32_16x16x32_bf16(kf, qaB, (f32x4){0.f,0.f,0.f,0.f}, 0, 0, 0);
        }
        __builtin_amdgcn_s_setprio(0);

        // ---- P = 2^S, pack to bf16 pairs (A then B to cap live range)
        unsigned int pkA0[8], pkA1[8], pkB0[8], pkB1[8];
        #pragma unroll
        for (int g = 0; g < 8; ++g) {
            #pragma unroll
            for (int r = 0; r < 4; ++r) sA[g][r] = fast_exp2(sA[g][r]);
            pkA0[g] = cvt_pk_bf16(sA[g][0], sA[g][1]);
            pkA1[g] = cvt_pk_bf16(sA[g][2], sA[g][3]);
        }
        #pragma unroll
        for (int g = 0; g < 8; ++g) {
            #pragma unroll
            for (int r = 0; r < 4; ++r) sB[g][r] = fast_exp2(sB[g][r]);
            pkB0[g] = cvt_pk_bf16(sB[g][0], sB[g][1]);
            pkB1[g] = cvt_pk_bf16(sB[g][2], sB[g][3]);
        }

        // ---- PV: assemble A-frags for both q-tiles; vf reads shared
        __builtin_amdgcn_s_setprio(1);
        #pragma unroll
        for (int c = 0; c < 4; ++c) {
            unsigned int zA0 = upperhalf ? pkA0[4 + c] : pkA0[4 + (c ^ 1)];
            unsigned int zA1 = upperhalf ? pkA1[4 + c] : pkA1[4 + (c ^ 1)];
            unsigned int zB0 = upperhalf ? pkB0[4 + c] : pkB0[4 + (c ^ 1)];
            unsigned int zB1 = upperhalf ? pkB1[4 + c] : pkB1[4 + (c ^ 1)];
            unsigned int rA0 = (unsigned int)__shfl_xor((int)zA0, 32);
            unsigned int rA1 = (unsigned int)__shfl_xor((int)zA1, 32);
            unsigned int rB0 = (unsigned int)__shfl_xor((int)zB0, 32);
            unsigned int rB1 = (unsigned int)__shfl_xor((int)zB1, 32);
            u32x4 fvA = {pkA0[c], pkA1[c], rA0, rA1};
            u32x4 fvB = {pkB0[c], pkB1[c], rB0, rB1};
            short8 fragA = __builtin_bit_cast(short8, fvA);
            short8 fragB = __builtin_bit_cast(short8, fvB);

            short8 vf0 = *(const short8*)&Vs[buf][(0 * 16 + lo) * 128 + ((c * 4 + hi) ^ lo) * 8];
            short8 vf1 = *(const short8*)&Vs[buf][(1 * 16 + lo) * 128 + ((c * 4 + hi) ^ lo) * 8];

            laccA = __builtin_amdgcn_mfma_f32_16x16x32_bf16(fragA, ones, laccA, 0, 0, 0);
            laccB = __builtin_amdgcn_mfma_f32_16x16x32_bf16(fragB, ones, laccB, 0, 0, 0);
            oaccA[0] = __builtin_amdgcn_mfma_f32_16x16x32_bf16(fragA, vf0, oaccA[0], 0, 0, 0);
            oaccA[1] = __builtin_amdgcn_mfma_f32_16x16x32_bf16(fragA, vf1, oaccA[1], 0, 0, 0);
            oaccB[0] = __builtin_amdgcn_mfma_f32_16x16x32_bf16(fragB, vf0, oaccB[0], 0, 0, 0);
            oaccB[1] = __builtin_amdgcn_mfma_f32_16x16x32_bf16(fragB, vf1, oaccB[1], 0, 0, 0);
        }
        __builtin_amdgcn_s_setprio(0);

        __syncthreads();             // all waves done reading buf; stage(buf^1) drained
        buf ^= 1;
    }

    // ---- store partials (unnormalized). Opart tile layout [d=32][row=16].
    {
        size_t tidx = (((size_t)bh * QT + qtA) * NSPLIT + split);
        float* ob = Opart + tidx * (HD * 16);
        #pragma unroll
        for (int df = 0; df < 2; ++df)
            *(f32x4*)&ob[(df * 16 + lo) * 16 + hi * 4] = oaccA[df];
        if (lo == 0) {
            float* lb = Lpart + tidx * 16;
            #pragma unroll
            for (int r = 0; r < 4; ++r) lb[hi * 4 + r] = laccA[r];
        }
    }
    {
        size_t tidx = (((size_t)bh * QT + qtB) * NSPLIT + split);
        float* ob = Opart + tidx * (HD * 16);
        #pragma unroll
        for (int df = 0; df < 2; ++df)
            *(f32x4*)&ob[(df * 16 + lo) * 16 + hi * 4] = oaccB[df];
        if (lo == 0) {
            float* lb = Lpart + tidx * 16;
            #pragma unroll
            for (int r = 0; r < 4; ++r) lb[hi * 4 + r] = laccB[r];
        }
    }
}

// ---------------------------------------------------------------------------
// Merge split-K partials: omT[b][n][h*32+d] = sum_s Opart / sum_s Lpart.
// ---------------------------------------------------------------------------
__global__ __launch_bounds__(256) void attn_merge(
    const float* __restrict__ Opart,
    const float* __restrict__ Lpart,
    unsigned short* __restrict__ omT)
{
    int bh = blockIdx.y, b = bh >> 3, h = bh & 7;
    int qt = blockIdx.x, n0 = qt * 16;
    int t = threadIdx.x;
    int d = t & 31;
    int r0 = t >> 5;                 // 0..7
    size_t base = ((size_t)bh * QT + qt) * NSPLIT;
    #pragma unroll
    for (int i = 0; i < 2; ++i) {
        int row = r0 + i * 8;
        float osum = 0.f, lsum = 0.f;
        #pragma unroll
        for (int s = 0; s < NSPLIT; ++s) {
            osum += Opart[(base + s) * (HD * 16) + d * 16 + row];
            lsum += Lpart[(base + s) * 16 + row];
        }
        omT[((size_t)b * NPOS + n0 + row) * CH + h * HD + d] = f2bf(osum / lsum);
    }
}

// ---------------------------------------------------------------------------
// Wo GEMM via bf16 MFMA: out fp32 [B][C][N] = Wo . omT^T + bo.
// Block = 4 waves, tile 32o x 64n; wave owns 16o x 32n. Grid 576 blocks.
// ---------------------------------------------------------------------------
__global__ __launch_bounds__(256) void wo_gemm(
    const unsigned short* __restrict__ omT,
    const unsigned short* __restrict__ Wo,
    const float* __restrict__ bo,
    float* __restrict__ out)
{
    int b = blockIdx.z;
    int n0 = blockIdx.x * 64;            // 36
    int o0 = blockIdx.y * 32;            // 8
    int t = threadIdx.x, w = t >> 6, lane = t & 63;
    int lo = lane & 15, hi = lane >> 4;
    int ob = o0 + (w & 1) * 16;
    int nb = n0 + (w >> 1) * 32;

    const unsigned short* xb = omT + ((size_t)b * NPOS + nb) * CH;

    f32x4 acc[2] = {};
    for (int k0 = 0; k0 < CH; k0 += 32) {
        short8 wf = *(const short8*)&Wo[(size_t)(ob + lo) * CH + k0 + hi * 8];
        #pragma unroll
        for (int g = 0; g < 2; ++g) {
            short8 xf = *(const short8*)&xb[(size_t)(g * 16 + lo) * CH + k0 + hi * 8];
            acc[g] = __builtin_amdgcn_mfma_f32_16x16x32_bf16(wf, xf, acc[g], 0, 0, 0);
        }
    }

    #pragma unroll
    for (int g = 0; g < 2; ++g) {
        int n = nb + g * 16 + lo;
        #pragma unroll
        for (int r = 0; r < 4; ++r) {
            int o = ob + hi * 4 + r;
            out[((size_t)b * CH + o) * NPOS + n] = acc[g][r] + bo[o];
        }
    }
}

// ---------------------------------------------------------------------------
extern "C" void kernel_launch(void* const* d_in, const int* in_sizes, int n_in,
                              void* d_out, int out_size, void* d_ws, size_t ws_size,
                              hipStream_t stream) {
    const float* x  = (const float*)d_in[0];
    const float* Wq = (const float*)d_in[1];
    const float* bq = (const float*)d_in[2];
    const float* Wk = (const float*)d_in[3];
    const float* bk = (const float*)d_in[4];
    const float* Wv = (const float*)d_in[5];
    const float* bv = (const float*)d_in[6];
    const float* Wo = (const float*)d_in[7];
    const float* bo = (const float*)d_in[8];
    float* out = (float*)d_out;

    const size_t E  = (size_t)BATCH * CH * NPOS;   // 1,179,648
    const size_t WS = (size_t)CH * CH;             // 65,536
    unsigned short* wbf = (unsigned short*)d_ws;   // 4 weight matrices bf16
    unsigned short* xT  = wbf + 4 * WS;            // [B][N][C] bf16
    unsigned short* qb  = xT + E;                  // [bh][N][32] bf16 (QSCALE'd)
    unsigned short* kb  = qb + E;                  // [bh][N][32] bf16
    unsigned short* vT  = kb + E;                  // [bh][32][N] bf16 (pi-permuted)
    float* Opart = (float*)(vT + E);               // 16*QT*NSPLIT*512 f32
    float* Lpart = Opart + (size_t)16 * QT * NSPLIT * (HD * 16);
    unsigned short* om = xT;                       // alias: xT dead after qkv_gemm
    (void)ws_size; (void)in_sizes; (void)n_in; (void)out_size;

    hipLaunchKernelGGL(prep, dim3(256 + 1152), dim3(256), 0, stream,
                       Wq, Wk, Wv, Wo, x, wbf, xT);
    hipLaunchKernelGGL(qkv_gemm, dim3(NPOS / 64, CH / 32, BATCH), dim3(256), 0, stream,
                       xT, wbf, bq, bk, bv, qb, kb, vT);
    hipLaunchKernelGGL(attn_split, dim3(NSPLIT * 16, QT / 8), dim3(256), 0, stream,
                       qb, kb, vT, Opart, Lpart);
    hipLaunchKernelGGL(attn_merge, dim3(QT, BATCH * NH), dim3(256), 0, stream,
                       Opart, Lpart, om);
    hipLaunchKernelGGL(wo_gemm, dim3(NPOS / 64, CH / 32, BATCH), dim3(256), 0, stream,
                       om, wbf + 3 * WS, bo, out);
}

// Round 12
// 64.402 us; speedup vs baseline: 1.1286x; 1.1286x over previous
//
#include <hip/hip_runtime.h>
#include <hip/hip_bf16.h>

// Problem constants
#define BATCH 2
#define CH 256
#define NH 8
#define HD 32
#define NPOS 2304            // 48*48
#define SCALE 0.17677669529663687f          // 32^-0.5
#define QSCALE 0.25503482f                  // SCALE * log2(e)
#define NSPLIT 3
#define KSPAN (NPOS / NSPLIT)               // 768 = 6 tiles of 128
#define NT (KSPAN / 128)                    // 6
#define QT (NPOS / 16)                      // 144 q-tiles
#define OMPAD 264                            // om LDS row pitch (shorts)

typedef __attribute__((ext_vector_type(8))) short short8;   // 8 x bf16 (4 VGPRs)
typedef __attribute__((ext_vector_type(4))) short short4e;  // 4 x bf16 (8B)
typedef __attribute__((ext_vector_type(4))) float f32x4;
typedef __attribute__((ext_vector_type(4))) unsigned int u32x4;
typedef __attribute__((ext_vector_type(2))) unsigned int u32x2;

__device__ __forceinline__ unsigned short f2bf(float f) {
    unsigned int u = __builtin_bit_cast(unsigned int, f);
    u += 0x7FFFu + ((u >> 16) & 1u);     // round-to-nearest-even
    return (unsigned short)(u >> 16);
}

// packed 2xbf16 <- 2xf32 (D.lo = cvt(a), D.hi = cvt(b)), RNE
__device__ __forceinline__ unsigned int cvt_pk_bf16(float a, float b) {
    unsigned int r;
    asm("v_cvt_pk_bf16_f32 %0, %1, %2" : "=v"(r) : "v"(a), "v"(b));
    return r;
}

// single-instruction 2^x
__device__ __forceinline__ float fast_exp2(float x) {
    float r;
    asm("v_exp_f32 %0, %1" : "=v"(r) : "v"(x));
    return r;
}

// async global->LDS, 16B per lane; LDS dest = uniform base + lane*16
#define GLOAD_LDS16(gsrc, ldst) \
    __builtin_amdgcn_global_load_lds( \
        (const __attribute__((address_space(1))) void*)(gsrc), \
        (__attribute__((address_space(3))) void*)(ldst), 16, 0, 0)

// ---------------------------------------------------------------------------
// Prep: fused weight-convert (blocks 0..255) + x transpose (blocks 256..1407).
// ---------------------------------------------------------------------------
__global__ __launch_bounds__(256) void prep(
    const float* __restrict__ Wq, const float* __restrict__ Wk,
    const float* __restrict__ Wv, const float* __restrict__ Wo,
    const float* __restrict__ x,
    unsigned short* __restrict__ wbf, unsigned short* __restrict__ xT)
{
    __shared__ float Ts[32][33];
    int id = blockIdx.x;
    int t = threadIdx.x;
    if (id < 256) {
        int which = id >> 6;
        const float* src = (which == 0) ? Wq : (which == 1) ? Wk : (which == 2) ? Wv : Wo;
        unsigned short* d = wbf + (size_t)which * CH * CH;
        int i = ((id & 63) * 256 + t) * 4;
        f32x4 v = *(const f32x4*)&src[i];
        short4e o;
        #pragma unroll
        for (int j = 0; j < 4; ++j) o[j] = (short)f2bf(v[j]);
        *(short4e*)&d[i] = o;
    } else {
        int tid = id - 256;
        int b = tid / 576;
        int rem = tid % 576;
        int c0 = (rem / 72) * 32;
        int n0 = (rem % 72) * 32;
        int col = t & 31, row = t >> 5;      // row 0..7
        #pragma unroll
        for (int i = 0; i < 4; ++i)
            Ts[row + i * 8][col] = x[((size_t)b * CH + c0 + row + i * 8) * NPOS + n0 + col];
        __syncthreads();
        #pragma unroll
        for (int i = 0; i < 4; ++i)
            xT[((size_t)b * NPOS + n0 + row + i * 8) * CH + c0 + col] = f2bf(Ts[col][row + i * 8]);
    }
}

// ---------------------------------------------------------------------------
// Fused QKV GEMM via bf16 MFMA. xT: [B][N][C] bf16. Wb: q|k|v bf16 [o][c].
// q,k bf16 [(b*NH+h)*N + n]*32 + d   (q pre-scaled by QSCALE = SCALE*log2e)
// v  bf16 [(b*NH+h)*32 + d]*N + pi(n)   (transposed, key-permuted per 128-blk)
// Block = 4 waves, tile 32o x 64n; wave owns 16o x 32n. Grid 576 blocks.
// V store: in-quad 4x4 shfl transpose -> one 8B store/lane/g.
// ---------------------------------------------------------------------------
__global__ __launch_bounds__(256) void qkv_gemm(
    const unsigned short* __restrict__ xT,
    const unsigned short* __restrict__ Wb,
    const float* __restrict__ bq, const float* __restrict__ bk,
    const float* __restrict__ bv,
    unsigned short* __restrict__ qout, unsigned short* __restrict__ kout,
    unsigned short* __restrict__ vout)
{
    int b = blockIdx.z;
    int n0 = blockIdx.x * 64;            // 36
    int o0 = blockIdx.y * 32;            // 8
    int t = threadIdx.x, w = t >> 6, lane = t & 63;
    int lo = lane & 15, hi = lane >> 4;
    int ob = o0 + (w & 1) * 16;
    int nb = n0 + (w >> 1) * 32;

    const unsigned short* Wq = Wb;
    const unsigned short* Wk = Wb + (size_t)CH * CH;
    const unsigned short* Wv = Wb + (size_t)2 * CH * CH;
    const unsigned short* xb = xT + ((size_t)b * NPOS + nb) * CH;

    f32x4 aq[2] = {}, ak[2] = {}, av[2] = {};

    for (int k0 = 0; k0 < CH; k0 += 32) {
        short8 wqf = *(const short8*)&Wq[(size_t)(ob + lo) * CH + k0 + hi * 8];
        short8 wkf = *(const short8*)&Wk[(size_t)(ob + lo) * CH + k0 + hi * 8];
        short8 wvf = *(const short8*)&Wv[(size_t)(ob + lo) * CH + k0 + hi * 8];
        #pragma unroll
        for (int g = 0; g < 2; ++g) {
            short8 xf = *(const short8*)&xb[(size_t)(g * 16 + lo) * CH + k0 + hi * 8];
            aq[g] = __builtin_amdgcn_mfma_f32_16x16x32_bf16(wqf, xf, aq[g], 0, 0, 0);
            ak[g] = __builtin_amdgcn_mfma_f32_16x16x32_bf16(wkf, xf, ak[g], 0, 0, 0);
            av[g] = __builtin_amdgcn_mfma_f32_16x16x32_bf16(wvf, xf, av[g], 0, 0, 0);
        }
    }

    int h = ob >> 5;
    int olow = (ob & 31) + hi * 4;
    int rr = lo & 3, qd = lo >> 2;
    #pragma unroll
    for (int g = 0; g < 2; ++g) {
        int n = nb + g * 16 + lo;
        size_t qkbase = ((size_t)(b * NH + h) * NPOS + n) * HD + olow;
        short4e pq, pk;
        #pragma unroll
        for (int r = 0; r < 4; ++r) {
            int o = ob + hi * 4 + r;
            pq[r] = (short)f2bf((aq[g][r] + bq[o]) * QSCALE);
            pk[r] = (short)f2bf(ak[g][r] + bk[o]);
        }
        *(short4e*)&qout[qkbase] = pq;
        *(short4e*)&kout[qkbase] = pk;

        // ---- V store: bias-add, 4x4 transpose across quad lanes, 8B store
        float v0 = av[g][0] + bv[ob + hi * 4 + 0];
        float v1 = av[g][1] + bv[ob + hi * 4 + 1];
        float v2 = av[g][2] + bv[ob + hi * 4 + 2];
        float v3 = av[g][3] + bv[ob + hi * 4 + 3];
        float p, r_;
        p = (rr & 1) ? v0 : v1; r_ = __shfl_xor(p, 1); if (rr & 1) v0 = r_; else v1 = r_;
        p = (rr & 1) ? v2 : v3; r_ = __shfl_xor(p, 1); if (rr & 1) v2 = r_; else v3 = r_;
        p = (rr & 2) ? v0 : v2; r_ = __shfl_xor(p, 2); if (rr & 2) v0 = r_; else v2 = r_;
        p = (rr & 2) ? v1 : v3; r_ = __shfl_xor(p, 2); if (rr & 2) v1 = r_; else v3 = r_;
        u32x2 pr;
        pr[0] = cvt_pk_bf16(v0, v1);
        pr[1] = cvt_pk_bf16(v2, v3);
        int nbase = nb + g * 16;             // 16-aligned
        int G = (nbase & 127) >> 4;          // key-group of this 16-run
        int pbase;
        if (G < 4) {
            pbase = G * 32 + qd * 8;
        } else {
            int gam = G & 3;
            pbase = (qd >= 2) ? (gam * 32 + (qd - 2) * 8 + 4)
                              : ((gam ^ 1) * 32 + (qd + 2) * 8 + 4);
        }
        int d = (ob & 31) + hi * 4 + rr;
        size_t vaddr = ((size_t)(b * NH + h) * HD + d) * NPOS + (nbase & ~127) + pbase;
        *(u32x2*)&vout[vaddr] = pr;
    }
}

// ---------------------------------------------------------------------------
// Flash attention partial, bf16 MFMA, 128-key tiles, split-K x3.
// 4 waves/block share K/V tiles staged in LDS via global_load_lds (16B),
// double-buffered, one __syncthreads per tile.
// LDS source-pre-swizzled (K: blk^=row&3, V: blk^=row&15); swapped QK^T ->
// P lane-local; cvt_pk + one shfl_xor(32)/word with pi baked into V storage.
// grid (48, 36): id = x + 48y, 48%8==0 -> same (bh,split) -> same XCD.
// ---------------------------------------------------------------------------
__global__ __launch_bounds__(256) void attn_split(
    const unsigned short* __restrict__ Q,
    const unsigned short* __restrict__ K,
    const unsigned short* __restrict__ V,
    float* __restrict__ Opart,
    float* __restrict__ Lpart)
{
    const int N = NPOS;
    int xb_ = blockIdx.x;           // 0..47: (split, bh)
    int bh = xb_ & 15;
    int split = xb_ >> 4;           // 0..2
    int w = threadIdx.x >> 6;
    int qt = blockIdx.y * 4 + w;    // 0..143
    int n0 = qt * 16;
    int lane = threadIdx.x & 63;
    int lo = lane & 15, hi = lane >> 4;
    bool upperhalf = lane >= 32;

    // double-buffered K/V tiles: 8KB each per buffer (32KB total)
    __shared__ unsigned short Ks[2][128 * HD];
    __shared__ unsigned short Vs[2][HD * 128];

    short8 qa = *(const short8*)(Q + ((size_t)bh * N + n0 + lo) * HD + hi * 8);

    const unsigned short* Kb = K + (size_t)bh * N * HD;
    const unsigned short* Vb = V + (size_t)bh * HD * N;

    short8 ones;
    #pragma unroll
    for (int j = 0; j < 8; ++j) ones[j] = (short)0x3F80;   // bf16 1.0

    f32x4 oacc[2] = {{0.f,0.f,0.f,0.f},{0.f,0.f,0.f,0.f}};
    f32x4 lacc = {0.f,0.f,0.f,0.f};

    const int kbeg = split * KSPAN;

    // ---- staging: wave w covers chunks [w*128, w*128+128) of each 512-chunk tile
    auto stage = [&](int bidx, int k0) {
        #pragma unroll
        for (int j = 0; j < 2; ++j) {
            int L = w * 128 + j * 64 + lane;           // K chunk: row=L>>2, blk=L&3
            int row = L >> 2, blk = L & 3;
            const unsigned short* src = Kb + (size_t)(k0 + row) * HD + (blk ^ (row & 3)) * 8;
            GLOAD_LDS16(src, &Ks[bidx][(size_t)(w * 128 + j * 64) * 8]);
        }
        #pragma unroll
        for (int j = 0; j < 2; ++j) {
            int L = w * 128 + j * 64 + lane;           // V chunk: row=L>>4, blk=L&15
            int row = L >> 4, blk = L & 15;
            const unsigned short* src = Vb + (size_t)row * N + k0 + (blk ^ (row & 15)) * 8;
            GLOAD_LDS16(src, &Vs[bidx][(size_t)(w * 128 + j * 64) * 8]);
        }
    };

    // prologue: stage tile 0
    stage(0, kbeg);
    __syncthreads();                 // drains vmcnt + barrier

    int buf = 0;
    #pragma unroll
    for (int kt = 0; kt < NT; ++kt) {
        int k0 = kbeg + kt * 128;
        if (kt + 1 < NT) stage(buf ^ 1, k0 + 128);

        // ---- S^T = K Q^T from LDS (swizzled read): lane -> P[q=lo][key g*16+hi*4+r]
        f32x4 s[8];
        __builtin_amdgcn_s_setprio(1);
        #pragma unroll
        for (int g = 0; g < 8; ++g) {
            short8 kf = *(const short8*)&Ks[buf][(g * 16 + lo) * HD + (hi ^ (lo & 3)) * 8];
            s[g] = __builtin_amdgcn_mfma_f32_16x16x32_bf16(kf, qa, (f32x4){0.f,0.f,0.f,0.f}, 0, 0, 0);
        }
        __builtin_amdgcn_s_setprio(0);

        // ---- P = 2^S (no max shift; Q carries SCALE*log2e)
        #pragma unroll
        for (int g = 0; g < 8; ++g)
            #pragma unroll
            for (int r = 0; r < 4; ++r)
                s[g][r] = fast_exp2(s[g][r]);

        // ---- pack to bf16 pairs
        unsigned int pk0[8], pk1[8];
        #pragma unroll
        for (int g = 0; g < 8; ++g) {
            pk0[g] = cvt_pk_bf16(s[g][0], s[g][1]);
            pk1[g] = cvt_pk_bf16(s[g][2], s[g][3]);
        }

        // ---- assemble PV A-frags: own groups 0-3 + partner(lane^32) groups 4-7
        __builtin_amdgcn_s_setprio(1);
        #pragma unroll
        for (int c = 0; c < 4; ++c) {
            unsigned int z0 = upperhalf ? pk0[4 + c] : pk0[4 + (c ^ 1)];
            unsigned int z1 = upperhalf ? pk1[4 + c] : pk1[4 + (c ^ 1)];
            unsigned int r0 = (unsigned int)__shfl_xor((int)z0, 32);
            unsigned int r1 = (unsigned int)__shfl_xor((int)z1, 32);
            u32x4 fv = {pk0[c], pk1[c], r0, r1};
            short8 frag = __builtin_bit_cast(short8, fv);

            lacc = __builtin_amdgcn_mfma_f32_16x16x32_bf16(frag, ones, lacc, 0, 0, 0);
            #pragma unroll
            for (int df = 0; df < 2; ++df) {
                short8 vf = *(const short8*)&Vs[buf][(df * 16 + lo) * 128 + ((c * 4 + hi) ^ lo) * 8];
                oacc[df] = __builtin_amdgcn_mfma_f32_16x16x32_bf16(frag, vf, oacc[df], 0, 0, 0);
            }
        }
        __builtin_amdgcn_s_setprio(0);

        __syncthreads();             // all waves done reading buf; stage(buf^1) drained
        buf ^= 1;
    }

    // ---- store partials (unnormalized). Opart tile layout [d=32][row=16].
    size_t tidx  = (((size_t)bh * QT + qt) * NSPLIT + split);
    float* ob = Opart + tidx * (HD * 16);
    #pragma unroll
    for (int df = 0; df < 2; ++df)
        *(f32x4*)&ob[(df * 16 + lo) * 16 + hi * 4] = oacc[df];
    if (lo == 0) {
        float* lb = Lpart + tidx * 16;
        #pragma unroll
        for (int r = 0; r < 4; ++r) lb[hi * 4 + r] = lacc[r];
    }
}

// ---------------------------------------------------------------------------
// Fused merge + Wo GEMM. Block (qt, b) owns 16 n-rows, ALL heads.
// Phase 1: thread c sums Opart over splits, divides by Lsum, writes bf16
//          om tile [16][OMPAD] to LDS (same f2bf rounding as before).
// Phase 2: out[b][o][n] = Wo . om^T + bo; A-frags from global Wo (L2-hot),
//          B-frags from LDS (row pitch 528B -> 2-way bank alias, free).
// ---------------------------------------------------------------------------
__global__ __launch_bounds__(256) void merge_wo(
    const float* __restrict__ Opart,
    const float* __restrict__ Lpart,
    const unsigned short* __restrict__ Wo,
    const float* __restrict__ bo,
    float* __restrict__ out)
{
    int qt = blockIdx.x;             // 0..143
    int b  = blockIdx.y;             // 0..1
    int t = threadIdx.x;

    __shared__ unsigned short omL[16 * OMPAD];

    // ---- phase 1: c = t (one channel per thread)
    {
        int c = t;
        int h = c >> 5, d = c & 31;
        size_t tbase = (((size_t)(b * NH + h) * QT + qt) * NSPLIT);
        float osum[16];
        #pragma unroll
        for (int j = 0; j < 4; ++j) {
            f32x4 a0 = *(const f32x4*)&Opart[(tbase + 0) * (HD * 16) + d * 16 + j * 4];
            f32x4 a1 = *(const f32x4*)&Opart[(tbase + 1) * (HD * 16) + d * 16 + j * 4];
            f32x4 a2 = *(const f32x4*)&Opart[(tbase + 2) * (HD * 16) + d * 16 + j * 4];
            #pragma unroll
            for (int r = 0; r < 4; ++r) osum[j * 4 + r] = a0[r] + a1[r] + a2[r];
        }
        float linv[16];
        #pragma unroll
        for (int j = 0; j < 4; ++j) {
            f32x4 l0 = *(const f32x4*)&Lpart[(tbase + 0) * 16 + j * 4];
            f32x4 l1 = *(const f32x4*)&Lpart[(tbase + 1) * 16 + j * 4];
            f32x4 l2 = *(const f32x4*)&Lpart[(tbase + 2) * 16 + j * 4];
            #pragma unroll
            for (int r = 0; r < 4; ++r) linv[j * 4 + r] = 1.f / (l0[r] + l1[r] + l2[r]);
        }
        #pragma unroll
        for (int r = 0; r < 16; ++r)
            omL[r * OMPAD + c] = f2bf(osum[r] * linv[r]);
    }
    __syncthreads();

    // ---- phase 2: wave w -> o rows [w*64, w*64+64)
    int w = t >> 6, lane = t & 63;
    int lo = lane & 15, hi = lane >> 4;
    int ow = w * 64;

    f32x4 acc[4] = {};
    #pragma unroll
    for (int k0 = 0; k0 < CH; k0 += 32) {
        short8 bfr = *(const short8*)&omL[lo * OMPAD + k0 + hi * 8];
        #pragma unroll
        for (int f = 0; f < 4; ++f) {
            short8 wf = *(const short8*)&Wo[(size_t)(ow + f * 16 + lo) * CH + k0 + hi * 8];
            acc[f] = __builtin_amdgcn_mfma_f32_16x16x32_bf16(wf, bfr, acc[f], 0, 0, 0);
        }
    }

    int n = qt * 16 + lo;
    #pragma unroll
    for (int f = 0; f < 4; ++f) {
        #pragma unroll
        for (int r = 0; r < 4; ++r) {
            int o = ow + f * 16 + hi * 4 + r;
            out[((size_t)b * CH + o) * NPOS + n] = acc[f][r] + bo[o];
        }
    }
}

// ---------------------------------------------------------------------------
extern "C" void kernel_launch(void* const* d_in, const int* in_sizes, int n_in,
                              void* d_out, int out_size, void* d_ws, size_t ws_size,
                              hipStream_t stream) {
    const float* x  = (const float*)d_in[0];
    const float* Wq = (const float*)d_in[1];
    const float* bq = (const float*)d_in[2];
    const float* Wk = (const float*)d_in[3];
    const float* bk = (const float*)d_in[4];
    const float* Wv = (const float*)d_in[5];
    const float* bv = (const float*)d_in[6];
    const float* Wo = (const float*)d_in[7];
    const float* bo = (const float*)d_in[8];
    float* out = (float*)d_out;

    const size_t E  = (size_t)BATCH * CH * NPOS;   // 1,179,648
    const size_t WS = (size_t)CH * CH;             // 65,536
    unsigned short* wbf = (unsigned short*)d_ws;   // 4 weight matrices bf16
    unsigned short* xT  = wbf + 4 * WS;            // [B][N][C] bf16
    unsigned short* qb  = xT + E;                  // [bh][N][32] bf16 (QSCALE'd)
    unsigned short* kb  = qb + E;                  // [bh][N][32] bf16
    unsigned short* vT  = kb + E;                  // [bh][32][N] bf16 (pi-permuted)
    float* Opart = (float*)(vT + E);               // 16*QT*NSPLIT*512 f32
    float* Lpart = Opart + (size_t)16 * QT * NSPLIT * (HD * 16);
    (void)ws_size; (void)in_sizes; (void)n_in; (void)out_size;

    hipLaunchKernelGGL(prep, dim3(256 + 1152), dim3(256), 0, stream,
                       Wq, Wk, Wv, Wo, x, wbf, xT);
    hipLaunchKernelGGL(qkv_gemm, dim3(NPOS / 64, CH / 32, BATCH), dim3(256), 0, stream,
                       xT, wbf, bq, bk, bv, qb, kb, vT);
    hipLaunchKernelGGL(attn_split, dim3(NSPLIT * 16, QT / 4), dim3(256), 0, stream,
                       qb, kb, vT, Opart, Lpart);
    hipLaunchKernelGGL(merge_wo, dim3(QT, BATCH), dim3(256), 0, stream,
                       Opart, Lpart, wbf + 3 * WS, bo, out);
}